// Round 9
// baseline (300.452 us; speedup 1.0000x reference)
//
#include <hip/hip_runtime.h>
#include <hip/hip_bf16.h>
#include <cstdint>
#include <cstddef>

typedef __bf16 bf16_t;
typedef bf16_t bf16x8 __attribute__((ext_vector_type(8)));
typedef bf16_t bf16x4 __attribute__((ext_vector_type(4)));
typedef float f32x4 __attribute__((ext_vector_type(4)));

#define NB 8
#define NT 1024
#define NC 1024
#define NH 16
#define ND 64
#define NTP 64

// ---------------- fused cast fp32 -> bf16 for x and prefix (one launch) ----------------
__global__ __launch_bounds__(256) void k_cast2(const float* __restrict__ a, bf16_t* __restrict__ da,
                                               int n4a,
                                               const float* __restrict__ b2, bf16_t* __restrict__ db,
                                               int n4b) {
    int i = blockIdx.x * 256 + threadIdx.x;
    if (i < n4a) {
        float4 f = ((const float4*)a)[i];
        bf16x4 o;
        o[0] = (bf16_t)f.x; o[1] = (bf16_t)f.y; o[2] = (bf16_t)f.z; o[3] = (bf16_t)f.w;
        ((bf16x4*)da)[i] = o;
    } else {
        int j = i - n4a;
        if (j < n4b) {
            float4 f = ((const float4*)b2)[j];
            bf16x4 o;
            o[0] = (bf16_t)f.x; o[1] = (bf16_t)f.y; o[2] = (bf16_t)f.z; o[3] = (bf16_t)f.w;
            ((bf16x4*)db)[j] = o;
        }
    }
}

// ------- all 3 weight transposes (K,N) fp32 -> (N,K) bf16 in ONE launch -------
__global__ __launch_bounds__(256) void k_transpose3(const float* __restrict__ s0, bf16_t* __restrict__ d0,
                                                    const float* __restrict__ s1, bf16_t* __restrict__ d1,
                                                    const float* __restrict__ s2, bf16_t* __restrict__ d2) {
    __shared__ float tile[32][33];
    const int z = blockIdx.z;
    const float* src = (z == 0) ? s0 : (z == 1) ? s1 : s2;
    bf16_t* dst = (z == 0) ? d0 : (z == 1) ? d1 : d2;
    const int N = (z == 2) ? NC : 3 * NC;
    const int K = NC;
    if (z == 2 && blockIdx.x >= 32) return;
    int nt = blockIdx.x, kt = blockIdx.y;
    int tx = threadIdx.x & 31;
    int ty = threadIdx.x >> 5;  // 0..7
#pragma unroll
    for (int i = 0; i < 4; i++) {
        int r = ty + i * 8;
        tile[r][tx] = src[(size_t)(kt * 32 + r) * N + nt * 32 + tx];
    }
    __syncthreads();
#pragma unroll
    for (int i = 0; i < 4; i++) {
        int r = ty + i * 8;
        dst[(size_t)(nt * 32 + r) * K + kt * 32 + tx] = (bf16_t)tile[tx][r];
    }
}

// ---------------- merged qkv + pqkv GEMM (grid 24 x 68, DEFAULT block order) ----------------
// by<64: qkv = xb @ wTa + b_attn (M=8192, TSH=10). by>=64: pqkv = pb @ wTp + b_prefix
// (M=512, TSH=6). cols>=2048 (V third) stored via bijective transposed-tile remap
// (fuses k_vT; attention reads V through the same map).
// NOTE (R8 lesson): default dispatch with gridDim.x=24 (%8==0) already pins each
// B-column-panel to a fixed XCD (XCD = bx%8) -- chunked wgid swizzle REGRESSED
// FETCH 77->103 MB. Do not re-add a swizzle here.
__global__ __launch_bounds__(256) void k_gemm_qkv(const bf16_t* __restrict__ xb,
                                                  const bf16_t* __restrict__ pb,
                                                  const bf16_t* __restrict__ wTa,
                                                  const bf16_t* __restrict__ wTp,
                                                  const float* __restrict__ b_attn,
                                                  const float* __restrict__ b_prefix,
                                                  bf16_t* __restrict__ qkv,
                                                  bf16_t* __restrict__ pqkv) {
    const int bx = blockIdx.x;
    const int byw = blockIdx.y;
    const bool pre = (byw >= 64);
    const bf16_t* A = pre ? pb : xb;
    const bf16_t* BT = pre ? wTp : wTa;
    const float* bias = pre ? b_prefix : b_attn;
    bf16_t* Cout = pre ? pqkv : qkv;
    const int tsh = pre ? 6 : 10;
    const size_t rowA0 = (size_t)(pre ? (byw - 64) : byw) * 128;
    const size_t colB0 = (size_t)bx * 128;
    const int K = NC, N = 3 * NC;

    __shared__ bf16_t As[128 * 72];
    __shared__ bf16_t Bs[128 * 72];
    const int tid = threadIdx.x;
    const int lane = tid & 63;
    const int wave = tid >> 6;
    const int quad = lane >> 4;
    const int l15 = lane & 15;
    const int wm = (wave >> 1) * 64;
    const int wn = (wave & 1) * 64;

    const f32x4 fz = {0.f, 0.f, 0.f, 0.f};
    f32x4 acc[4][4];
#pragma unroll
    for (int i = 0; i < 4; i++)
#pragma unroll
        for (int j = 0; j < 4; j++) acc[i][j] = fz;

    for (int k0 = 0; k0 < K; k0 += 64) {
        __syncthreads();
#pragma unroll
        for (int i = 0; i < 4; i++) {
            int c = tid + i * 256;
            int r = c >> 3;
            int kc = (c & 7) * 8;
            uint4 av = *(const uint4*)(A + (rowA0 + r) * (size_t)K + k0 + kc);
            *(uint4*)(&As[r * 72 + kc]) = av;
            uint4 bv = *(const uint4*)(BT + (colB0 + r) * (size_t)K + k0 + kc);
            *(uint4*)(&Bs[r * 72 + kc]) = bv;
        }
        __syncthreads();
#pragma unroll
        for (int kk = 0; kk < 2; kk++) {
            bf16x8 af[4], bfr[4];
#pragma unroll
            for (int i = 0; i < 4; i++)
                af[i] = *(const bf16x8*)(&As[(wm + i * 16 + l15) * 72 + kk * 32 + quad * 8]);
#pragma unroll
            for (int j = 0; j < 4; j++)
                bfr[j] = *(const bf16x8*)(&Bs[(wn + j * 16 + l15) * 72 + kk * 32 + quad * 8]);
#pragma unroll
            for (int i = 0; i < 4; i++)
#pragma unroll
                for (int j = 0; j < 4; j++)
                    acc[i][j] = __builtin_amdgcn_mfma_f32_16x16x32_bf16(af[i], bfr[j], acc[i][j], 0, 0, 0);
        }
    }
    const bool vpath = (colB0 >= (size_t)(2 * NC));
#pragma unroll
    for (int i = 0; i < 4; i++) {
        size_t row = rowA0 + wm + i * 16 + quad * 4;
#pragma unroll
        for (int j = 0; j < 4; j++) {
            int col = (int)colB0 + wn + j * 16 + l15;
            float bv = bias[col];
            if (vpath) {
                int hh = (col - 2 * NC) >> 6;
                int dd = col & 63;
                int bb = (int)(row >> tsh);
                int tt = (int)row & ((1 << tsh) - 1);
                int tileBase = (bb * NH + hh) * (1 << (tsh - 6)) + (tt >> 6);
                size_t chunkrow = (size_t)tileBase * 4 + (dd >> 4);
                size_t addr = chunkrow * (size_t)N + 2 * NC + (dd & 15) * 64 + (tt & 63);
                bf16x4 vv;
#pragma unroll
                for (int r = 0; r < 4; r++) vv[r] = (bf16_t)(acc[i][j][r] + bv);
                *(bf16x4*)(Cout + addr) = vv;
            } else {
#pragma unroll
                for (int r = 0; r < 4; r++) {
                    float v = acc[i][j][r] + bv;
                    Cout[(row + r) * (size_t)N + col] = (bf16_t)v;
                }
            }
        }
    }
}

// ---------------- proj GEMM: out(f32) = yb @ wTpr + b_proj (XCD-swizzled) ----------------
__global__ __launch_bounds__(256) void k_gemm_proj(const bf16_t* __restrict__ A,
                                                   const bf16_t* __restrict__ BT,
                                                   const float* __restrict__ bias,
                                                   float* __restrict__ Cout,
                                                   int M, int N, int K) {
    // T1 XCD swizzle (nwg = gridDim.x*gridDim.y, %8==0) — part of R8's winning bundle.
    const int nwg = gridDim.x * gridDim.y;
    const int flat = blockIdx.y * gridDim.x + blockIdx.x;
    const int wgid = (flat & 7) * (nwg >> 3) + (flat >> 3);
    const int bx = wgid % gridDim.x;
    const int byw = wgid / gridDim.x;
    const size_t rowA0 = (size_t)byw * 128;
    const size_t colB0 = (size_t)bx * 128;

    __shared__ bf16_t As[128 * 72];
    __shared__ bf16_t Bs[128 * 72];
    const int tid = threadIdx.x;
    const int lane = tid & 63;
    const int wave = tid >> 6;
    const int quad = lane >> 4;
    const int l15 = lane & 15;
    const int wm = (wave >> 1) * 64;
    const int wn = (wave & 1) * 64;

    const f32x4 fz = {0.f, 0.f, 0.f, 0.f};
    f32x4 acc[4][4];
#pragma unroll
    for (int i = 0; i < 4; i++)
#pragma unroll
        for (int j = 0; j < 4; j++) acc[i][j] = fz;

    for (int k0 = 0; k0 < K; k0 += 64) {
        __syncthreads();
#pragma unroll
        for (int i = 0; i < 4; i++) {
            int c = tid + i * 256;
            int r = c >> 3;
            int kc = (c & 7) * 8;
            uint4 av = *(const uint4*)(A + (rowA0 + r) * (size_t)K + k0 + kc);
            *(uint4*)(&As[r * 72 + kc]) = av;
            uint4 bv = *(const uint4*)(BT + (colB0 + r) * (size_t)K + k0 + kc);
            *(uint4*)(&Bs[r * 72 + kc]) = bv;
        }
        __syncthreads();
#pragma unroll
        for (int kk = 0; kk < 2; kk++) {
            bf16x8 af[4], bfr[4];
#pragma unroll
            for (int i = 0; i < 4; i++)
                af[i] = *(const bf16x8*)(&As[(wm + i * 16 + l15) * 72 + kk * 32 + quad * 8]);
#pragma unroll
            for (int j = 0; j < 4; j++)
                bfr[j] = *(const bf16x8*)(&Bs[(wn + j * 16 + l15) * 72 + kk * 32 + quad * 8]);
#pragma unroll
            for (int i = 0; i < 4; i++)
#pragma unroll
                for (int j = 0; j < 4; j++)
                    acc[i][j] = __builtin_amdgcn_mfma_f32_16x16x32_bf16(af[i], bfr[j], acc[i][j], 0, 0, 0);
        }
    }
#pragma unroll
    for (int i = 0; i < 4; i++) {
        size_t row = rowA0 + wm + i * 16 + quad * 4;
#pragma unroll
        for (int j = 0; j < 4; j++) {
            int col = (int)colB0 + wn + j * 16 + l15;
            float bv = bias[col];
#pragma unroll
            for (int r = 0; r < 4; r++)
                Cout[(row + r) * (size_t)N + col] = acc[i][j][r] + bv;
        }
    }
}

// ---------------- fused dual-softmax causal attention (R8, unchanged) ------------
#define LOADREGS(KB, VCB)                                                            \
    rk0 = *(const uint4*)((KB) + (size_t)(tid >> 3) * 3072 + (tid & 7) * 8);         \
    rv0 = *(const uint4*)((VCB) + (size_t)(tid >> 7) * 3072 + (tid & 127) * 8);

#define STAGE(KS, VS)                                                \
    *(uint4*)(&(KS)[(tid >> 3) * 72 + (tid & 7) * 8]) = rk0;         \
    *(uint4*)(&(VS)[(tid >> 3) * 72 + (tid & 7) * 8]) = rv0;

#define QK(KS, Sj, j)                                                                  \
    Sj = __builtin_amdgcn_mfma_f32_16x16x32_bf16(                                      \
        aq0, *(const bf16x8*)(&(KS)[((j) * 16 + l15) * 72 + quad * 8]), Sj, 0, 0, 0);  \
    Sj = __builtin_amdgcn_mfma_f32_16x16x32_bf16(                                      \
        aq1, *(const bf16x8*)(&(KS)[((j) * 16 + l15) * 72 + 32 + quad * 8]), Sj, 0, 0, 0);

#define EXPJ(Sj, j, BL, LACC)                                           \
    {                                                                   \
        const int n_ = (j) * 16 + l15;                                  \
        _Pragma("unroll") for (int r_ = 0; r_ < 4; r_++) {              \
            float p_ = __expf(Sj[r_] * scale);                          \
            if (n_ > (BL) + r_) p_ = 0.f;                               \
            Sj[r_] = p_;                                                \
            LACC[r_] += p_;                                             \
        }                                                               \
    }

#define PSTORE(Sj, j)                                                   \
    _Pragma("unroll") for (int r_ = 0; r_ < 4; r_++)                    \
        P[(quad * 4 + r_) * 72 + (j) * 16 + l15] = (bf16_t)Sj[r_];

#define PV(VS, Oj, j)                                                                  \
    Oj = __builtin_amdgcn_mfma_f32_16x16x32_bf16(                                      \
        ap0, *(const bf16x8*)(&(VS)[((j) * 16 + l15) * 72 + quad * 8]), Oj, 0, 0, 0);  \
    Oj = __builtin_amdgcn_mfma_f32_16x16x32_bf16(                                      \
        ap1, *(const bf16x8*)(&(VS)[((j) * 16 + l15) * 72 + 32 + quad * 8]), Oj, 0, 0, 0);

#define PROC(KS, VS, BL, LACC, O0, O1, O2, O3)                          \
    {                                                                   \
        f32x4 S0 = fz, S1 = fz, S2 = fz, S3 = fz;                       \
        __builtin_amdgcn_s_setprio(1);                                  \
        QK(KS, S0, 0) QK(KS, S1, 1) QK(KS, S2, 2) QK(KS, S3, 3)         \
        __builtin_amdgcn_s_setprio(0);                                  \
        EXPJ(S0, 0, BL, LACC) EXPJ(S1, 1, BL, LACC)                     \
        EXPJ(S2, 2, BL, LACC) EXPJ(S3, 3, BL, LACC)                     \
        PSTORE(S0, 0) PSTORE(S1, 1) PSTORE(S2, 2) PSTORE(S3, 3)         \
        __builtin_amdgcn_s_waitcnt(0xc07f); /* lgkmcnt(0) */            \
        __builtin_amdgcn_wave_barrier();                                \
        bf16x8 ap0 = *(const bf16x8*)(&P[l15 * 72 + quad * 8]);         \
        bf16x8 ap1 = *(const bf16x8*)(&P[l15 * 72 + 32 + quad * 8]);    \
        __builtin_amdgcn_s_setprio(1);                                  \
        PV(VS, O0, 0) PV(VS, O1, 1) PV(VS, O2, 2) PV(VS, O3, 3)         \
        __builtin_amdgcn_s_setprio(0);                                  \
    }

#define STORE_O(Oj, Pj, j)                                                            \
    _Pragma("unroll") for (int r_ = 0; r_ < 4; r_++) {                                \
        float v_ = Oj[r_] * lmv[r_] + Pj[r_] * lpv[r_];                               \
        y[(qrow0 + quad * 4 + r_) * NC + h * 64 + (j) * 16 + l15] = (bf16_t)v_;       \
    }

__global__ __launch_bounds__(512, 2) void k_attn11(const bf16_t* __restrict__ qkv,
                                                   const bf16_t* __restrict__ pqkv,
                                                   bf16_t* __restrict__ y) {
    // T1 XCD swizzle over flat grid (8,16,8) = 1024 blocks: XCD x <-> batch x
    // (K/V working set 4MB = one L2); LPT preserved (x=0 -> largest qt first).
    const int flat = (int)blockIdx.x + 8 * ((int)blockIdx.y + 16 * (int)blockIdx.z);
    const int wgid = (flat & 7) * 128 + (flat >> 3);
    const int qt = (NT / 128 - 1) - (wgid & 7);
    const int h = (wgid >> 3) & 15;
    const int b = wgid >> 7;
    const int TMAX = 2 * qt + 1;  // last main tile index

    __shared__ bf16_t Ks0[64 * 72], Ks1[64 * 72];
    __shared__ bf16_t Vs0[64 * 72], Vs1[64 * 72];
    __shared__ bf16_t Ps[8][16 * 72];

    const int tid = threadIdx.x;
    const int lane = tid & 63;
    const int wave = tid >> 6;       // 0..7
    const int quad = lane >> 4;
    const int l15 = lane & 15;
    const float scale = 0.125f;      // 1/sqrt(64)

    const size_t qrow0 = (size_t)b * NT + (size_t)qt * 128 + wave * 16;
    const int qoff = qt * 128 + wave * 16 + quad * 4;  // q row (within b) of acc slot r=0
    bf16_t* P = Ps[wave];

    const bf16_t* Kmain = qkv + (size_t)(b * NT) * 3072 + NC + h * 64;
    const bf16_t* Vmain = qkv + (size_t)(b * NH + h) * 16 * 4 * 3072 + 2 * NC;
    const bf16_t* Vpre  = pqkv + (size_t)(b * NH + h) * 4 * 3072 + 2 * NC;

    bf16x8 aq0 = *(const bf16x8*)(qkv + (qrow0 + l15) * 3072 + h * 64 + quad * 8);
    bf16x8 aq1 = *(const bf16x8*)(qkv + (qrow0 + l15) * 3072 + h * 64 + 32 + quad * 8);

    const f32x4 fz = {0.f, 0.f, 0.f, 0.f};
    f32x4 Om0 = fz, Om1 = fz, Om2 = fz, Om3 = fz;
    f32x4 Op0 = fz, Op1 = fz, Op2 = fz, Op3 = fz;
    f32x4 Lm = fz, Lp = fz;
    uint4 rk0, rv0;

    LOADREGS(pqkv + (size_t)(b * NTP) * 3072 + NC + h * 64, Vpre)
    STAGE(Ks0, Vs0)
    LOADREGS(Kmain, Vmain)
    __syncthreads();
    PROC(Ks0, Vs0, qoff, Lp, Op0, Op1, Op2, Op3)
    STAGE(Ks1, Vs1)
    LOADREGS(Kmain + (size_t)64 * 3072, Vmain + 4 * 3072)

    for (int t = 0; t <= TMAX; t++) {
        __syncthreads();
        bf16_t* KSc = (t & 1) ? Ks0 : Ks1;
        bf16_t* VSc = (t & 1) ? Vs0 : Vs1;
        if (t < TMAX) {
            bf16_t* KSn = (t & 1) ? Ks1 : Ks0;
            bf16_t* VSn = (t & 1) ? Vs1 : Vs0;
            STAGE(KSn, VSn)
        }
        if (t + 1 < TMAX) {
            LOADREGS(Kmain + ((size_t)(t + 2) * 64) * 3072, Vmain + (size_t)(t + 2) * 4 * 3072)
        }
        PROC(KSc, VSc, qoff - t * 64, Lm, Om0, Om1, Om2, Om3)
    }

    f32x4 lmv, lpv;
#pragma unroll
    for (int r = 0; r < 4; r++) {
        float vm = Lm[r], vpr = Lp[r];
#pragma unroll
        for (int off = 1; off < 16; off <<= 1) {
            vm += __shfl_xor(vm, off, 64);
            vpr += __shfl_xor(vpr, off, 64);
        }
        lmv[r] = 1.0f / vm;
        lpv[r] = 1.0f / vpr;
    }

    STORE_O(Om0, Op0, 0) STORE_O(Om1, Op1, 1) STORE_O(Om2, Op2, 2) STORE_O(Om3, Op3, 3)
}

// ---------------- launch ----------------
extern "C" void kernel_launch(void* const* d_in, const int* in_sizes, int n_in,
                              void* d_out, int out_size, void* d_ws, size_t ws_size,
                              hipStream_t stream) {
    (void)in_sizes; (void)n_in; (void)out_size; (void)ws_size;
    const float* x        = (const float*)d_in[0];
    const float* prefix   = (const float*)d_in[1];
    const float* w_attn   = (const float*)d_in[2];
    const float* b_attn   = (const float*)d_in[3];
    const float* w_prefix = (const float*)d_in[4];
    const float* b_prefix = (const float*)d_in[5];
    const float* w_proj   = (const float*)d_in[6];
    const float* b_proj   = (const float*)d_in[7];
    float* out = (float*)d_out;

    char* p = (char*)d_ws;
    auto carve = [&](size_t bytes) {
        char* q = p;
        p += (bytes + 255) & ~(size_t)255;
        return q;
    };
    bf16_t* xb   = (bf16_t*)carve((size_t)NB * NT * NC * 2);        // 16 MB
    bf16_t* pb   = (bf16_t*)carve((size_t)NB * NTP * NC * 2);       // 1 MB
    bf16_t* wTa  = (bf16_t*)carve((size_t)3 * NC * NC * 2);         // 6 MB
    bf16_t* wTp  = (bf16_t*)carve((size_t)3 * NC * NC * 2);         // 6 MB
    bf16_t* wTpr = (bf16_t*)carve((size_t)NC * NC * 2);             // 2 MB
    bf16_t* qkv  = (bf16_t*)carve((size_t)NB * NT * 3 * NC * 2);    // 48 MB (V third = tiled V)
    bf16_t* pqkv = (bf16_t*)carve((size_t)NB * NTP * 3 * NC * 2);   // 3 MB (V third = tiled V)
    bf16_t* yb   = (bf16_t*)carve((size_t)NB * NT * NC * 2);        // 16 MB

    const int n4a = NB * NT * NC / 4, n4b = NB * NTP * NC / 4;
    k_cast2<<<(n4a + n4b + 255) / 256, 256, 0, stream>>>(x, xb, n4a, prefix, pb, n4b);
    k_transpose3<<<dim3(3 * NC / 32, NC / 32, 3), 256, 0, stream>>>(w_attn, wTa, w_prefix, wTp,
                                                                    w_proj, wTpr);
    // merged qkv + pqkv GEMM (default block order; V thirds -> transposed tile layout)
    k_gemm_qkv<<<dim3(24, 68), 256, 0, stream>>>(xb, pb, wTa, wTp, b_attn, b_prefix, qkv, pqkv);
    // attention (QBLK=128, 8 waves, XCD-swizzled)
    k_attn11<<<dim3(NT / 128, NH, NB), 512, 0, stream>>>(qkv, pqkv, yb);
    // out = y @ w_proj + b_proj (fp32 out, XCD-swizzled)
    k_gemm_proj<<<dim3(NC / 128, NB * NT / 128), 256, 0, stream>>>(
        yb, wTpr, b_proj, out, NB * NT, NC, NC);
}